// Round 9
// baseline (95.457 us; speedup 1.0000x reference)
//
#include <hip/hip_runtime.h>
#include <math.h>

#define EPSF 1e-8f

typedef __attribute__((ext_vector_type(4))) short short4v;
typedef __attribute__((ext_vector_type(8))) short short8v;
typedef __attribute__((ext_vector_type(4))) float float4v;

__device__ inline short f2bf(float f) {
    unsigned u = __builtin_bit_cast(unsigned, f);
    unsigned r = (u + 0x7FFFu + ((u >> 16) & 1u)) >> 16;
    return (short)r;
}
__device__ inline float bf2f(short s) {
    unsigned u = ((unsigned)(unsigned short)s) << 16;
    return __builtin_bit_cast(float, u);
}

// F layout (bf16 shorts): f1t @0 (4*128*4096), f1s @2097152, f2t @4194304
// (4*256*1024), f2s @5242880; total 6291456 shorts = 12.6 MB.
#define F1T 0
#define F1S 2097152
#define F2T 4194304
#define F2S 5242880

// Gram trick: ||S1-S2||_F^2 = ||AA^T||^2 - 2||AB^T||^2 + ||BB^T||^2 over c x c
// grams (k = hw). 128x128 tiles (full-matrix sums). g1 (c=128): whole gram =
// one tile; 3 jobs/b {tt w1, ss w1, ts w-2}. g2 (c=256): 2x2 grid of
// 128-tiles; symmetric grams upper triangle w={1,2,1}, cross all 4 quads
// w=-2 -> 10 jobs/b. (geometry verified rounds 6/8, absmax=0)
__constant__ int g2q_tab[10][4] = {     // {type, qi, qj, w}
    {0,0,0,1},{0,0,1,2},{0,1,1,1},
    {1,0,0,1},{1,0,1,2},{1,1,1,1},
    {2,0,0,-2},{2,0,1,-2},{2,1,0,-2},{2,1,1,-2},
};

// ------------- prep: single-pass norm + normalize + bf16 convert -----------
// 1280 blocks x 32 px. (verified rounds 0-8)
template<int C, int HW>
__device__ inline void prep_body(const float* __restrict__ x,
                                 short* __restrict__ f, int lp, int t)
{
    const int lanei = t & 7, slice = t >> 3;     // 8 groups x 32 slices
    const int b = lp / HW, m = lp - b * HW;
    const float* p = x + (size_t)b * C * HW + m;
    short*       q = f + (size_t)b * C * HW + m;
    constexpr int CPR = C >> 5;          // rows per slice (4 or 8)
    short4v vals[CPR];
    float4 s0 = {0.f,0.f,0.f,0.f}, s1 = {0.f,0.f,0.f,0.f};
#pragma unroll
    for (int i = 0; i < CPR; i += 2) {
        float4 v0 = *(const float4*)(p + (size_t)(slice * CPR + i)     * HW);
        float4 v1 = *(const float4*)(p + (size_t)(slice * CPR + i + 1) * HW);
        s0.x += v0.x * v0.x; s0.y += v0.y * v0.y;
        s0.z += v0.z * v0.z; s0.w += v0.w * v0.w;
        s1.x += v1.x * v1.x; s1.y += v1.y * v1.y;
        s1.z += v1.z * v1.z; s1.w += v1.w * v1.w;
        vals[i]     = (short4v){ f2bf(v0.x), f2bf(v0.y), f2bf(v0.z), f2bf(v0.w) };
        vals[i + 1] = (short4v){ f2bf(v1.x), f2bf(v1.y), f2bf(v1.z), f2bf(v1.w) };
    }
    float4 s = { s0.x + s1.x, s0.y + s1.y, s0.z + s1.z, s0.w + s1.w };
    __shared__ float4 red[32][8];
    __shared__ float4 invl[8];
    red[slice][lanei] = s;
    __syncthreads();
    if (t < 8) {
        float4 tot = {0.f,0.f,0.f,0.f};
#pragma unroll
        for (int sl = 0; sl < 32; ++sl) {
            float4 v = red[sl][t];
            tot.x += v.x; tot.y += v.y; tot.z += v.z; tot.w += v.w;
        }
        invl[t] = (float4){ 1.f / (sqrtf(tot.x) + EPSF), 1.f / (sqrtf(tot.y) + EPSF),
                            1.f / (sqrtf(tot.z) + EPSF), 1.f / (sqrtf(tot.w) + EPSF) };
    }
    __syncthreads();
    const float4 iv = invl[lanei];
#pragma unroll
    for (int i = 0; i < CPR; ++i) {
        const int r = slice * CPR + i;
        short4v rv = vals[i];
        short4v o = { f2bf(bf2f(rv[0]) * iv.x), f2bf(bf2f(rv[1]) * iv.y),
                      f2bf(bf2f(rv[2]) * iv.z), f2bf(bf2f(rv[3]) * iv.w) };
        *(short4v*)(q + (size_t)r * HW) = o;
    }
}

__global__ __launch_bounds__(256) void prep_kernel(
    const float* __restrict__ x1t, const float* __restrict__ x1s,
    const float* __restrict__ x2t, const float* __restrict__ x2s,
    short* __restrict__ F, float* __restrict__ out,
    unsigned* __restrict__ cnt)
{
    const int gp = blockIdx.x * 32;
    const int t = threadIdx.x;
    const int lanei = t & 7;
    if (blockIdx.x == 0 && t < 4) out[t] = 0.f;   // replaces memset dispatch
    if (blockIdx.x == 0 && t == 4) *cnt = 0u;     // finalize counter reset
    if (gp < 16384)
        prep_body<128, 4096>(x1t, F + F1T, gp + lanei * 4, t);
    else if (gp < 32768)
        prep_body<128, 4096>(x1s, F + F1S, gp - 16384 + lanei * 4, t);
    else if (gp < 36864)
        prep_body<256, 1024>(x2t, F + F2T, gp - 32768 + lanei * 4, t);
    else
        prep_body<256, 1024>(x2s, F + F2S, gp - 36864 + lanei * 4, t);
}

// ------------- gram tile body: 128x128, k-chunk 256, depth-2 prefetch -----
// 4 stages of BK=64, fully unrolled, two named register sets (A/B ping-pong)
// so stage st+2's global loads issue while st computes (~2 stages of
// compute+barriers between issue and use covers L3 latency; round-8
// post-mortem: depth-1 couldn't hide it at 0.69 blocks/CU). Stage/compute
// maps byte-identical to the round-6/8 verified body. LDS row stride 72.
#define ASTR 72

template<int HW, bool SHARE>
__device__ inline void gram_tile128(const short* __restrict__ Fa,
                                    const short* __restrict__ Fb,
                                    int k0, int t,
                                    short* __restrict__ ldsA,
                                    short* __restrict__ ldsB,
                                    float4v (&acc)[4][4])
{
    const int lane = t & 63, w = t >> 6;
    const int r16 = lane & 15, quad = lane >> 4;
    const int wr = w >> 1, wc = w & 1;
    const int srow = t >> 3, skc = (t & 7) * 8;   // stage: 32 rows x 8 kcols

    short8v arA[4], brA[4], arB[4], brB[4];

    auto loadA = [&](short8v (&ra)[4], short8v (&rb)[4], int kk) {
#pragma unroll
        for (int p = 0; p < 4; ++p)
            ra[p] = *(const short8v*)(Fa + (size_t)(p * 32 + srow) * HW + kk + skc);
        if (!SHARE) {
#pragma unroll
            for (int p = 0; p < 4; ++p)
                rb[p] = *(const short8v*)(Fb + (size_t)(p * 32 + srow) * HW + kk + skc);
        }
    };
    auto store = [&](short8v (&ra)[4], short8v (&rb)[4]) {
#pragma unroll
        for (int p = 0; p < 4; ++p)
            *(short8v*)(ldsA + (p * 32 + srow) * ASTR + skc) = ra[p];
        if (!SHARE) {
#pragma unroll
            for (int p = 0; p < 4; ++p)
                *(short8v*)(ldsB + (p * 32 + srow) * ASTR + skc) = rb[p];
        }
    };
    auto compute = [&]() {
        const short* A = ldsA;
        const short* B = SHARE ? ldsA : ldsB;
#pragma unroll
        for (int ks = 0; ks < 2; ++ks) {
            short8v af[4], bf[4];
#pragma unroll
            for (int i = 0; i < 4; ++i)
                af[i] = *(const short8v*)(A + (wr * 64 + i * 16 + r16) * ASTR + ks * 32 + quad * 8);
#pragma unroll
            for (int j = 0; j < 4; ++j)
                bf[j] = *(const short8v*)(B + (wc * 64 + j * 16 + r16) * ASTR + ks * 32 + quad * 8);
#pragma unroll
            for (int i = 0; i < 4; ++i)
#pragma unroll
                for (int j = 0; j < 4; ++j)
                    acc[i][j] = __builtin_amdgcn_mfma_f32_16x16x32_bf16(
                        af[i], bf[j], acc[i][j], 0, 0, 0);
        }
    };

    loadA(arA, brA, k0);                 // prologue: stages 0,1 in flight
    loadA(arB, brB, k0 + 64);

    // stage 0 (set A); issue stage 2 -> A
    store(arA, brA); __syncthreads();
    loadA(arA, brA, k0 + 128);
    compute(); __syncthreads();
    // stage 1 (set B); issue stage 3 -> B
    store(arB, brB); __syncthreads();
    loadA(arB, brB, k0 + 192);
    compute(); __syncthreads();
    // stage 2 (set A)
    store(arA, brA); __syncthreads();
    compute(); __syncthreads();
    // stage 3 (set B)
    store(arB, brB); __syncthreads();
    compute();
    __syncthreads();
}

// ------------- gram kernel: 352 blocks x 256 thr; slab = blockIdx ---------
// g1 (id<192): jb=id/16 (type*4+b), ks=id%16, k0=ks*256. g2: id2=id-192,
// job=id2/4, ks=id2%4. All CUs covered (1.4 blocks/CU) + depth-2 prefetch
// attack the round-8 latency-serial stage chain.
__global__ __launch_bounds__(256, 2) void gram_kernel(
    const short* __restrict__ F, float* __restrict__ partials)
{
    __shared__ __align__(16) short ldsA[128 * ASTR];
    __shared__ __align__(16) short ldsB[128 * ASTR];

    const int id = blockIdx.x;
    const int t = threadIdx.x, w = t >> 6, lane = t & 63;
    const int r16 = lane & 15, quad = lane >> 4;
    const int wr = w >> 1, wc = w & 1;

    float4v acc[4][4];
#pragma unroll
    for (int i = 0; i < 4; ++i)
#pragma unroll
        for (int j = 0; j < 4; ++j) acc[i][j] = (float4v){0.f, 0.f, 0.f, 0.f};

    if (id < 192) {                      // group 1: c=128, k=4096
        const int jb = id >> 4, ks = id & 15;
        const int type = jb >> 2, b = jb & 3;
        const int k0 = ks * 256;
        const short* Fa = (type == 1 ? F + F1S : F + F1T) + (size_t)b * 524288;
        const short* Fb = (type == 0 ? F + F1T : F + F1S) + (size_t)b * 524288;
        if (type < 2) gram_tile128<4096, true >(Fa, Fa, k0, t, ldsA, ldsB, acc);
        else          gram_tile128<4096, false>(Fa, Fb, k0, t, ldsA, ldsB, acc);
    } else {                             // group 2: c=256, k=1024
        const int id2 = id - 192;
        const int job = id2 >> 2, ks = id2 & 3;
        const int b = job / 10, j10 = job - b * 10;
        const int type = g2q_tab[j10][0];
        const int qi = g2q_tab[j10][1], qj = g2q_tab[j10][2];
        const int k0 = ks * 256;
        const short* Fa = (type == 1 ? F + F2S : F + F2T)
                          + (size_t)(b * 256 + qi * 128) * 1024;
        const short* Fb = (type == 0 ? F + F2T : F + F2S)
                          + (size_t)(b * 256 + qj * 128) * 1024;
        if (type < 2 && qi == qj)
            gram_tile128<1024, true >(Fa, Fa, k0, t, ldsA, ldsB, acc);
        else
            gram_tile128<1024, false>(Fa, Fb, k0, t, ldsA, ldsB, acc);
    }

    // ---- write 128x128 fp32 k-partial slab (slab = blockIdx) --------------
    // C/D layout: col = lane&15, row = quad*4 + reg.
    float* dst = partials + (size_t)id * 16384;
#pragma unroll
    for (int i = 0; i < 4; ++i)
#pragma unroll
        for (int j = 0; j < 4; ++j)
#pragma unroll
            for (int r = 0; r < 4; ++r)
                dst[(wr * 64 + i * 16 + quad * 4 + r) * 128 + wc * 64 + j * 16 + r16]
                    = acc[i][j][r];
}

// ------------- finalize: 208 blocks (4/tile); unrolled P, r5 protocol ------
// g1 tile = 16 consecutive slabs (slabs jb*16..+15); g2 job = 4 slabs
// (192 + job*4..+3). Per thread: 4 coalesced float4s x P independent loads.
// One atomicAdd(out[which]) per block; global counter last-block writes
// out[0..1]. (protocol verified rounds 5/8)
template<int P>
__device__ inline float fin_sum(const float* __restrict__ base, int part, int t)
{
    float s = 0.f;
    const int off = part * 4096 + t * 4;
#pragma unroll
    for (int i = 0; i < 4; ++i) {
        const int idx = off + i * 1024;
        float4 v = {0.f, 0.f, 0.f, 0.f};
#pragma unroll
        for (int p = 0; p < P; ++p) {
            float4 u = *(const float4*)(base + (size_t)p * 16384 + idx);
            v.x += u.x; v.y += u.y; v.z += u.z; v.w += u.w;
        }
        s += v.x * v.x + v.y * v.y + v.z * v.z + v.w * v.w;
    }
    return s;
}

__global__ __launch_bounds__(256) void fin_kernel(
    const float* __restrict__ partials, float* __restrict__ out,
    unsigned* __restrict__ cnt)
{
    __shared__ float sc[4];
    const int bid = blockIdx.x;
    const int t = threadIdx.x, lane = t & 63, w = t >> 6;

    float s, wt; int which;
    if (bid < 48) {                      // g1: 12 tiles x 4 parts, P=16
        const int tile = bid >> 2, part = bid & 3;
        const int type = tile >> 2;
        s = fin_sum<16>(partials + (size_t)tile * 16 * 16384, part, t);
        wt = (type == 2 ? -2.f : 1.f) * (1.0f / (4096.f * 4096.f * 4.f));
        which = 2;
    } else {                             // g2: 40 jobs x 4 parts, P=4
        const int b2 = bid - 48;
        const int job = b2 >> 2, part = b2 & 3;
        const int j10 = job % 10;
        s = fin_sum<4>(partials + (size_t)(192 + job * 4) * 16384, part, t);
        wt = (float)g2q_tab[j10][3] * (1.0f / (1024.f * 1024.f * 4.f));
        which = 3;
    }
    s *= wt;

#pragma unroll
    for (int o = 32; o > 0; o >>= 1) s += __shfl_down(s, o);
    if (lane == 0) sc[w] = s;
    __syncthreads();
    if (t == 0) {
        float val = sc[0] + sc[1] + sc[2] + sc[3];
        atomicAdd(&out[which], val);     // stack[1]=pwl_g1 / stack[2]=pwl_g2
        __threadfence();                 // add visible before counter bump
        unsigned old = atomicAdd(cnt, 1u);
        if (old == 207u) {               // last block: finalize loss
            float g1v = __hip_atomic_load(&out[2], __ATOMIC_RELAXED,
                                          __HIP_MEMORY_SCOPE_AGENT);
            float g2v = __hip_atomic_load(&out[3], __ATOMIC_RELAXED,
                                          __HIP_MEMORY_SCOPE_AGENT);
            float loss = g1v + g2v;
            out[0] = loss;               // loss
            out[1] = loss;               // stack[0] = loss
        }
    }
}

extern "C" void kernel_launch(void* const* d_in, const int* in_sizes, int n_in,
                              void* d_out, int out_size, void* d_ws, size_t ws_size,
                              hipStream_t stream)
{
    const float* x1t = (const float*)d_in[0];   // [4,128,64,64]
    const float* x1s = (const float*)d_in[1];
    const float* x2t = (const float*)d_in[2];   // [4,256,32,32]
    const float* x2s = (const float*)d_in[3];

    short* F        = (short*)d_ws;              // 6291456 shorts (12.6 MB)
    float* partials = (float*)d_ws + 3200000;    // 352 x 16384 floats (23 MB)
    unsigned* cnt   = (unsigned*)((float*)d_ws + 9000000);

    prep_kernel<<<1280, 256, 0, stream>>>(x1t, x1s, x2t, x2s, F,
                                          (float*)d_out, cnt);
    gram_kernel<<<352, 256, 0, stream>>>(F, partials);
    fin_kernel<<<208, 256, 0, stream>>>(partials, (float*)d_out, cnt);
}